// Round 7
// baseline (1172.087 us; speedup 1.0000x reference)
//
#include <hip/hip_runtime.h>

typedef unsigned short u16;
typedef u16 u16x4 __attribute__((ext_vector_type(4)));
typedef u16 u16x8 __attribute__((ext_vector_type(8)));
typedef __bf16 bf16x8 __attribute__((ext_vector_type(8)));
typedef float f32x4 __attribute__((ext_vector_type(4)));

#define MFMA16 __builtin_amdgcn_mfma_f32_16x16x32_bf16
#define QSCALE 0.17677669529663689f
#define VMWAIT(N) asm volatile("s_waitcnt vmcnt(" #N ")" ::: "memory")

__device__ __forceinline__ u16 f2bf(float f) {
  unsigned u = __builtin_bit_cast(unsigned, f);
  u += 0x7fffu + ((u >> 16) & 1u);
  return (u16)(u >> 16);
}
__device__ __forceinline__ bf16x8 as_bf(u16x8 u) { return __builtin_bit_cast(bf16x8, u); }
__device__ __forceinline__ f32x4 zf4() { f32x4 z = {0.f, 0.f, 0.f, 0.f}; return z; }

template <int CTRL>
__device__ __forceinline__ float dppf(float x) {
  int i = __builtin_bit_cast(int, x);
  int r = __builtin_amdgcn_update_dpp(i, i, CTRL, 0xf, 0xf, false);
  return __builtin_bit_cast(float, r);
}
__device__ __forceinline__ float rmax16(float x) {
  x = fmaxf(x, dppf<0xB1>(x));
  x = fmaxf(x, dppf<0x4E>(x));
  x = fmaxf(x, dppf<0x124>(x));
  x = fmaxf(x, dppf<0x128>(x));
  return x;
}
__device__ __forceinline__ float rsum16(float x) {
  x += dppf<0xB1>(x);
  x += dppf<0x4E>(x);
  x += dppf<0x124>(x);
  x += dppf<0x128>(x);
  return x;
}

// ---------------- prep: weight transpose->bf16, smask build ----------------
__global__ __launch_bounds__(256) void prep_kernel(
    const float* __restrict__ wq, const float* __restrict__ wp,
    const float* __restrict__ bt, const int* __restrict__ ri,
    const float* __restrict__ mask,
    u16* __restrict__ wqT, u16* __restrict__ wpT, float* __restrict__ smask) {
  int idx = blockIdx.x * 256 + threadIdx.x;
  if (idx < 442368) {
    int nn = idx / 384, kk = idx % 384;
    wqT[idx] = f2bf(wq[(size_t)kk * 1152 + nn]);
  } else if (idx < 589824) {
    int i2 = idx - 442368;
    int nn = i2 / 384, kk = i2 % 384;
    wpT[i2] = f2bf(wp[(size_t)kk * 384 + nn]);
  } else if (idx < 705072) {
    int i3 = idx - 589824;
    int g = i3 / 28812;
    int rem = i3 % 28812;
    int h = rem / 2401;
    int nm = rem % 2401;
    smask[i3] = bt[ri[nm] * 12 + h] + mask[g * 2401 + nm];
  }
}

// ---------------- conv_x: fp32 x -> bf16 (one pass) ------------------------
__global__ __launch_bounds__(256) void conv_x(const float* __restrict__ x,
                                              u16* __restrict__ xb) {
  size_t i = ((size_t)blockIdx.x * 256 + threadIdx.x) * 8;
  f32x4 a = *(const f32x4*)(x + i);
  f32x4 b = *(const f32x4*)(x + i + 4);
  u16x8 o;
  o[0] = f2bf(a[0]); o[1] = f2bf(a[1]); o[2] = f2bf(a[2]); o[3] = f2bf(a[3]);
  o[4] = f2bf(b[0]); o[5] = f2bf(b[1]); o[6] = f2bf(b[2]); o[7] = f2bf(b[3]);
  *(u16x8*)(xb + i) = o;
}

// ---------------- GEMM v5: persistent blocks, depth-3 pipeline -------------
// C^T orientation: D[ch][tok].  128ch x 128tok tile, BK=32, 4 waves.
// Grid = 768 (3 blocks/CU resident); each block processes NT = 18|19 (qkv)
// or 6|7 (proj) tiles with ONE continuous pipeline: 3 LDS buffers, steady
// state VMWAIT(8) (2 stages in flight), tapering 8->4->0 only on the very
// last tile.  Bias in LDS (lgkm-counted) so epilogue doesn't perturb the
// vmcnt bookkeeping.  T2 swizzle as verified in v3/v4.
template <int NCH, int TPB8, bool QKV>
__global__ __launch_bounds__(256) void gemm5(
    const u16* __restrict__ Wt, const u16* __restrict__ Xb,
    const float* __restrict__ bias, void* __restrict__ outp) {
  __shared__ u16 As[3][128 * 32];
  __shared__ u16 Bs[3][128 * 32];
  __shared__ float LB[NCH * 128];
  const int t = threadIdx.x;
  const int l = t & 63, w = t >> 6;
  const int LDC = NCH * 128;

  // bias -> LDS (ordinary loads; drained by compiler + covered by loop barriers)
#pragma unroll
  for (int i = 0; i < (NCH * 128 + 1023) / 1024; ++i) {
    const int idx = i * 1024 + t * 4;
    if (idx < NCH * 128) *(f32x4*)(&LB[idx]) = *(const f32x4*)(bias + idx);
  }

  const int p = blockIdx.x;
  const int t0 = (p * TPB8) >> 3;
  const int NT = (((p + 1) * TPB8) >> 3) - t0;

  f32x4 acc[4][4];
#pragma unroll
  for (int mi = 0; mi < 4; ++mi)
#pragma unroll
    for (int ni = 0; ni < 4; ++ni) acc[mi][ni] = zf4();

  const int rA = (w >> 1) * 64 + (l & 15);
  const int rB = (w & 1) * 64 + (l & 15);
  const int gsel = l >> 4;
  const int gA = ((gsel ^ ((rA >> 1) & 3))) * 8;
  const int gB = ((gsel ^ ((rB >> 1) & 3))) * 8;

  // stage k-chunk kt of absolute tile ta into buffer bf
  auto stage = [&](int ta, int kt, int bf) {
    const int tokt = ta / NCH, cht = ta % NCH;
    const int tb = tokt * 128, cb = cht * 128;
    const int ko = kt * 32;
#pragma unroll
    for (int j = 0; j < 2; ++j) {
      const int gi = j * 256 + t;
      const int row = gi >> 2, slot = gi & 3;
      const int sg = (slot ^ ((row >> 1) & 3)) * 8;
      __builtin_amdgcn_global_load_lds(
          (const __attribute__((address_space(1))) unsigned int*)
              (Wt + (size_t)(cb + row) * 384 + ko + sg),
          (__attribute__((address_space(3))) unsigned int*)(&As[bf][gi * 8]),
          16, 0, 0);
      __builtin_amdgcn_global_load_lds(
          (const __attribute__((address_space(1))) unsigned int*)
              (Xb + (size_t)(tb + row) * 384 + ko + sg),
          (__attribute__((address_space(3))) unsigned int*)(&Bs[bf][gi * 8]),
          16, 0, 0);
    }
  };

  stage(t0, 0, 0);
  stage(t0, 1, 1);
  stage(t0, 2, 2);

  for (int T = 0; T < NT; ++T) {
    const int ta = t0 + T;
    const bool last = (T == NT - 1);
#pragma unroll
    for (int ks = 0; ks < 12; ++ks) {
      if (ks == 10) { if (last) { VMWAIT(4); } else { VMWAIT(8); } }
      else if (ks == 11) { if (last) { VMWAIT(0); } else { VMWAIT(8); } }
      else { VMWAIT(8); }
      __builtin_amdgcn_sched_barrier(0);
      __builtin_amdgcn_s_barrier();          // all waves' buf loads landed
      const int bf = ks % 3;
      bf16x8 af[4], bfr[4];
#pragma unroll
      for (int mi = 0; mi < 4; ++mi)
        af[mi] = *(const bf16x8*)(&As[bf][(rA + mi * 16) * 32 + gA]);
#pragma unroll
      for (int nj = 0; nj < 4; ++nj)
        bfr[nj] = *(const bf16x8*)(&Bs[bf][(rB + nj * 16) * 32 + gB]);
      asm volatile("s_waitcnt lgkmcnt(0)" ::: "memory");
      __builtin_amdgcn_sched_barrier(0);
      __builtin_amdgcn_s_barrier();          // all reads of buf retired
      if (ks < 9) stage(ta, ks + 3, bf);
      else if (!last) stage(ta + 1, ks - 9, bf);
      __builtin_amdgcn_sched_barrier(0);
      __builtin_amdgcn_s_setprio(1);
#pragma unroll
      for (int mi = 0; mi < 4; ++mi)
#pragma unroll
        for (int nj = 0; nj < 4; ++nj)
          acc[mi][nj] = MFMA16(af[mi], bfr[nj], acc[mi][nj], 0, 0, 0);
      __builtin_amdgcn_s_setprio(0);

      if (ks == 11) {
        // epilogue for tile ta; bias from LDS (lgkm, not vmcnt)
        const int tokt = ta / NCH, cht = ta % NCH;
        const int tb = tokt * 128, cb = cht * 128;
#pragma unroll
        for (int mi = 0; mi < 4; ++mi) {
          const int ch = cb + (w >> 1) * 64 + mi * 16 + (l >> 4) * 4;
          const f32x4 bv = *(const f32x4*)(&LB[ch]);
#pragma unroll
          for (int nj = 0; nj < 4; ++nj) {
            const int tok = tb + (w & 1) * 64 + nj * 16 + (l & 15);
            if constexpr (QKV) {
              const float scl = (ch < 384) ? QSCALE : 1.0f;
              u16x4 pk;
#pragma unroll
              for (int r = 0; r < 4; ++r) pk[r] = f2bf((acc[mi][nj][r] + bv[r]) * scl);
              *(u16x4*)((u16*)outp + (size_t)tok * LDC + ch) = pk;
            } else {
              f32x4 o;
#pragma unroll
              for (int r = 0; r < 4; ++r) o[r] = acc[mi][nj][r] + bv[r];
              *(f32x4*)((float*)outp + (size_t)tok * LDC + ch) = o;
            }
            acc[mi][nj] = zf4();
          }
        }
      }
    }
  }
}

// ---------------- Attention: per-window, per-head -------------------------
// PV as O^T = V^T @ P^T.  P stored 64-wide with granule-XOR swizzle
// (conflict-free b128 reads, no padding) -> 50.2 KB/block -> 3 blocks/CU.
__global__ __launch_bounds__(256) void attn_kernel(
    const u16* __restrict__ qkvb, const float* __restrict__ smask,
    u16* __restrict__ attnb) {
  __shared__ u16 Pl[4][64 * 64];   // P per wave: [n][k], granule-XOR swizzle
  __shared__ u16 Vt[4][2336];      // V^T per wave: [d][k], addr d*72+(d>>3)*8+k
  const int t = threadIdx.x;
  const int l = t & 63, w = t >> 6;
  const int b = blockIdx.x;
  u16* Pw = &Pl[w][0];
  u16* Vw = &Vt[w][0];

  for (int hi = 0; hi < 3; ++hi) {
    const int h = w + hi * 4;
    const u16* base = qkvb + (size_t)b * 49 * 1152 + h * 32 + (l >> 4) * 8;

    // V^T staging
#pragma unroll
    for (int i = 0; i < 4; ++i) {
      const int row = i * 16 + (l >> 2);
      const int sg = l & 3;
      u16x8 vv = {0, 0, 0, 0, 0, 0, 0, 0};
      if (row < 49)
        vv = *(const u16x8*)(qkvb + (size_t)(b * 49 + row) * 1152 + 768 + h * 32 + sg * 8);
#pragma unroll
      for (int e = 0; e < 8; ++e) {
        const int d = sg * 8 + e;
        Vw[d * 72 + (d >> 3) * 8 + row] = vv[e];
      }
    }

    // q (A-frag) / k (B-frag) from global
    bf16x8 qa[4], kb[4];
#pragma unroll
    for (int mi = 0; mi < 4; ++mi) {
      const int n = mi * 16 + (l & 15);
      u16x8 z = {0, 0, 0, 0, 0, 0, 0, 0};
      qa[mi] = (n < 49) ? *(const bf16x8*)(base + (size_t)n * 1152) : as_bf(z);
    }
#pragma unroll
    for (int nj = 0; nj < 4; ++nj) {
      const int m = nj * 16 + (l & 15);
      u16x8 z = {0, 0, 0, 0, 0, 0, 0, 0};
      kb[nj] = (m < 49) ? *(const bf16x8*)(base + 384 + (size_t)m * 1152) : as_bf(z);
    }

    // S = q k^T
    f32x4 s[4][4];
    __builtin_amdgcn_s_setprio(1);
#pragma unroll
    for (int mi = 0; mi < 4; ++mi)
#pragma unroll
      for (int nj = 0; nj < 4; ++nj) s[mi][nj] = MFMA16(qa[mi], kb[nj], zf4(), 0, 0, 0);
    __builtin_amdgcn_s_setprio(0);

    // bias + shift mask
    const float* sm = smask + ((size_t)(b & 3) * 12 + h) * 2401;
#pragma unroll
    for (int mi = 0; mi < 4; ++mi) {
#pragma unroll
      for (int r = 0; r < 4; ++r) {
        const int n = mi * 16 + (l >> 4) * 4 + r;
        if (n < 49) {
#pragma unroll
          for (int nj = 0; nj < 4; ++nj) {
            const int m = nj * 16 + (l & 15);
            s[mi][nj][r] = (m < 49) ? s[mi][nj][r] + sm[n * 49 + m] : -1e30f;
          }
        }
      }
    }
    // softmax (DPP reduce over 16-lane groups)
#pragma unroll
    for (int mi = 0; mi < 4; ++mi) {
#pragma unroll
      for (int r = 0; r < 4; ++r) {
        float mx = fmaxf(fmaxf(s[mi][0][r], s[mi][1][r]), fmaxf(s[mi][2][r], s[mi][3][r]));
        mx = rmax16(mx);
        float e0 = 0.f;
#pragma unroll
        for (int nj = 0; nj < 4; ++nj) {
          const float p = __expf(s[mi][nj][r] - mx);
          s[mi][nj][r] = p;
          e0 += p;
        }
        e0 = rsum16(e0);
        const float inv = 1.0f / e0;
#pragma unroll
        for (int nj = 0; nj < 4; ++nj) s[mi][nj][r] *= inv;
      }
    }
    // P -> LDS bf16, swizzled: addr = row*64 + ((col>>3)^(row&7))*8 + (col&7)
#pragma unroll
    for (int mi = 0; mi < 4; ++mi)
#pragma unroll
      for (int r = 0; r < 4; ++r) {
        const int row = mi * 16 + (l >> 4) * 4 + r;
#pragma unroll
        for (int nj = 0; nj < 4; ++nj) {
          const int col = nj * 16 + (l & 15);
          Pw[row * 64 + (((col >> 3) ^ (row & 7)) * 8) + (col & 7)] = f2bf(s[mi][nj][r]);
        }
      }
    asm volatile("s_waitcnt lgkmcnt(0)" ::: "memory");
    __builtin_amdgcn_sched_barrier(0);

    // O^T[d][n] = sum_k V^T[d][k] P^T[k][n]
    f32x4 ot[2][4];
#pragma unroll
    for (int dj = 0; dj < 2; ++dj)
#pragma unroll
      for (int mi = 0; mi < 4; ++mi) ot[dj][mi] = zf4();
#pragma unroll
    for (int ks = 0; ks < 2; ++ks) {
      bf16x8 va[2], pb[4];
#pragma unroll
      for (int dj = 0; dj < 2; ++dj) {
        const int d0 = dj * 16 + (l & 15);
        va[dj] = *(const bf16x8*)(Vw + d0 * 72 + (d0 >> 3) * 8 + ks * 32 + (l >> 4) * 8);
      }
#pragma unroll
      for (int mi = 0; mi < 4; ++mi) {
        const int row = mi * 16 + (l & 15);
        pb[mi] = *(const bf16x8*)(Pw + row * 64 + (((ks * 4 + (l >> 4)) ^ (l & 7)) * 8));
      }
      __builtin_amdgcn_s_setprio(1);
#pragma unroll
      for (int dj = 0; dj < 2; ++dj)
#pragma unroll
        for (int mi = 0; mi < 4; ++mi)
          ot[dj][mi] = MFMA16(va[dj], pb[mi], ot[dj][mi], 0, 0, 0);
      __builtin_amdgcn_s_setprio(0);
    }
    // store O^T
#pragma unroll
    for (int dj = 0; dj < 2; ++dj)
#pragma unroll
      for (int mi = 0; mi < 4; ++mi) {
        const int n = mi * 16 + (l & 15);
        if (n < 49) {
          u16x4 pk;
          pk[0] = f2bf(ot[dj][mi][0]);
          pk[1] = f2bf(ot[dj][mi][1]);
          pk[2] = f2bf(ot[dj][mi][2]);
          pk[3] = f2bf(ot[dj][mi][3]);
          *(u16x4*)(attnb + (size_t)(b * 49 + n) * 384 + h * 32 + dj * 16 + (l >> 4) * 4) = pk;
        }
      }
    asm volatile("s_waitcnt lgkmcnt(0)" ::: "memory");
    __builtin_amdgcn_sched_barrier(0);
  }
}

extern "C" void kernel_launch(void* const* d_in, const int* in_sizes, int n_in,
                              void* d_out, int out_size, void* d_ws, size_t ws_size,
                              hipStream_t stream) {
  const float* x       = (const float*)d_in[0];
  const float* mask    = (const float*)d_in[1];
  const float* w_qkv   = (const float*)d_in[2];
  const float* b_qkv   = (const float*)d_in[3];
  const float* bias_t  = (const float*)d_in[4];
  const float* w_proj  = (const float*)d_in[5];
  const float* b_proj  = (const float*)d_in[6];
  const int*   rel_idx = (const int*)d_in[7];
  float* out = (float*)d_out;

  char* ws = (char*)d_ws;
  u16*   wqT   = (u16*)ws;                       // 442368 u16
  u16*   wpT   = (u16*)(ws + 884736);            // 147456 u16
  float* smask = (float*)(ws + 1179648);         // 115248 f32
  u16*   qkvb  = (u16*)(ws + 1640640);           // 200704*1152 u16
  u16*   xb    = (u16*)(ws + 464062656);         // 200704*384 u16 (aliases attnb)
  u16*   attnb = (u16*)(ws + 464062656);         // xb dead before attn writes

  prep_kernel<<<2755, 256, 0, stream>>>(w_qkv, w_proj, bias_t, rel_idx, mask,
                                        wqT, wpT, smask);
  conv_x<<<37632, 256, 0, stream>>>(x, xb);
  // qkv: 14112 tiles over 768 blocks -> TPB8 = 14112*8/768 = 147
  gemm5<9, 147, true><<<768, 256, 0, stream>>>(wqT, xb, b_qkv, qkvb);
  attn_kernel<<<4096, 256, 0, stream>>>(qkvb, smask, attnb);
  // proj: 4704 tiles over 768 blocks -> TPB8 = 4704*8/768 = 49
  gemm5<3, 49, false><<<768, 256, 0, stream>>>(wpT, attnb, b_proj, out);
}

// Round 8
// 871.205 us; speedup vs baseline: 1.3454x; 1.3454x over previous
//
#include <hip/hip_runtime.h>

typedef unsigned short u16;
typedef u16 u16x4 __attribute__((ext_vector_type(4)));
typedef u16 u16x8 __attribute__((ext_vector_type(8)));
typedef __bf16 bf16x8 __attribute__((ext_vector_type(8)));
typedef float f32x4 __attribute__((ext_vector_type(4)));

#define MFMA16 __builtin_amdgcn_mfma_f32_16x16x32_bf16
#define QSCALE 0.17677669529663689f
#define VMWAIT(N) asm volatile("s_waitcnt vmcnt(" #N ")" ::: "memory")

__device__ __forceinline__ u16 f2bf(float f) {
  unsigned u = __builtin_bit_cast(unsigned, f);
  u += 0x7fffu + ((u >> 16) & 1u);
  return (u16)(u >> 16);
}
__device__ __forceinline__ bf16x8 as_bf(u16x8 u) { return __builtin_bit_cast(bf16x8, u); }
__device__ __forceinline__ f32x4 zf4() { f32x4 z = {0.f, 0.f, 0.f, 0.f}; return z; }

template <int CTRL>
__device__ __forceinline__ float dppf(float x) {
  int i = __builtin_bit_cast(int, x);
  int r = __builtin_amdgcn_update_dpp(i, i, CTRL, 0xf, 0xf, false);
  return __builtin_bit_cast(float, r);
}
__device__ __forceinline__ float rmax16(float x) {
  x = fmaxf(x, dppf<0xB1>(x));
  x = fmaxf(x, dppf<0x4E>(x));
  x = fmaxf(x, dppf<0x124>(x));
  x = fmaxf(x, dppf<0x128>(x));
  return x;
}
__device__ __forceinline__ float rsum16(float x) {
  x += dppf<0xB1>(x);
  x += dppf<0x4E>(x);
  x += dppf<0x124>(x);
  x += dppf<0x128>(x);
  return x;
}

// ---------------- prep: weight transpose->bf16, smask2 build ---------------
// smask2 layout: [g][h][n][lane(16)][nj(4)] where m = nj*16+lane, so a lane's
// 4 bias values for row n are one contiguous f32x4.  m>=49 / n>=49 -> 0.
__global__ __launch_bounds__(256) void prep_kernel(
    const float* __restrict__ wq, const float* __restrict__ wp,
    const float* __restrict__ bt, const int* __restrict__ ri,
    const float* __restrict__ mask,
    u16* __restrict__ wqT, u16* __restrict__ wpT, float* __restrict__ smask2) {
  int idx = blockIdx.x * 256 + threadIdx.x;
  if (idx < 442368) {
    int nn = idx / 384, kk = idx % 384;
    wqT[idx] = f2bf(wq[(size_t)kk * 1152 + nn]);
  } else if (idx < 589824) {
    int i2 = idx - 442368;
    int nn = i2 / 384, kk = i2 % 384;
    wpT[i2] = f2bf(wp[(size_t)kk * 384 + nn]);
  } else if (idx < 740352) {
    int i3 = idx - 589824;
    int g = i3 / 37632;
    int rem = i3 % 37632;
    int h = rem / 3136;
    int nm = rem % 3136;
    int n = nm >> 6;
    int r2 = nm & 63;
    int lane = r2 >> 2, nj = r2 & 3;
    int m = nj * 16 + lane;
    float v = 0.f;
    if (m < 49 && n < 49)
      v = bt[ri[n * 49 + m] * 12 + h] + mask[g * 2401 + n * 49 + m];
    smask2[i3] = v;
  }
}

// ---------------- conv_x: fp32 x -> bf16 (one pass) ------------------------
__global__ __launch_bounds__(256) void conv_x(const float* __restrict__ x,
                                              u16* __restrict__ xb) {
  size_t i = ((size_t)blockIdx.x * 256 + threadIdx.x) * 8;
  f32x4 a = *(const f32x4*)(x + i);
  f32x4 b = *(const f32x4*)(x + i + 4);
  u16x8 o;
  o[0] = f2bf(a[0]); o[1] = f2bf(a[1]); o[2] = f2bf(a[2]); o[3] = f2bf(a[3]);
  o[4] = f2bf(b[0]); o[5] = f2bf(b[1]); o[6] = f2bf(b[2]); o[7] = f2bf(b[3]);
  *(u16x8*)(xb + i) = o;
}

// ---------------- GEMM v4 (round-6 verified): C^T, BK=32, counted vmcnt ----
template <int NCH, bool QKV>
__global__ __launch_bounds__(256) void gemm4(
    const u16* __restrict__ Wt, const u16* __restrict__ Xb,
    const float* __restrict__ bias, void* __restrict__ outp) {
  __shared__ u16 As[2][128 * 32];
  __shared__ u16 Bs[2][128 * 32];
  const int t = threadIdx.x;
  const int l = t & 63, w = t >> 6;

  const int bid = blockIdx.x;
  const int xcd = bid & 7, q = bid >> 3;
  const int logical = xcd * (196 * NCH) + q;
  const int tokt = logical / NCH, cht = logical % NCH;
  const int tb = tokt * 128;
  const int cb = cht * 128;
  const int LDC = NCH * 128;

  f32x4 acc[4][4];
#pragma unroll
  for (int mi = 0; mi < 4; ++mi)
#pragma unroll
    for (int ni = 0; ni < 4; ++ni) acc[mi][ni] = zf4();

  const int rA = (w >> 1) * 64 + (l & 15);
  const int rB = (w & 1) * 64 + (l & 15);
  const int gsel = l >> 4;
  const int gA = ((gsel ^ ((rA >> 1) & 3))) * 8;
  const int gB = ((gsel ^ ((rB >> 1) & 3))) * 8;

  auto stage = [&](int bf, int kt) {
    const int ko = kt * 32;
#pragma unroll
    for (int j = 0; j < 2; ++j) {
      const int gi = j * 256 + t;
      const int row = gi >> 2, slot = gi & 3;
      const int sg = (slot ^ ((row >> 1) & 3)) * 8;
      __builtin_amdgcn_global_load_lds(
          (const __attribute__((address_space(1))) unsigned int*)
              (Wt + (size_t)(cb + row) * 384 + ko + sg),
          (__attribute__((address_space(3))) unsigned int*)(&As[bf][gi * 8]),
          16, 0, 0);
      __builtin_amdgcn_global_load_lds(
          (const __attribute__((address_space(1))) unsigned int*)
              (Xb + (size_t)(tb + row) * 384 + ko + sg),
          (__attribute__((address_space(3))) unsigned int*)(&Bs[bf][gi * 8]),
          16, 0, 0);
    }
  };

  auto kbody = [&](int cur, int ktnext, bool dostage) {
    __builtin_amdgcn_sched_barrier(0);
    __builtin_amdgcn_s_barrier();
    bf16x8 af[4], bfr[4];
#pragma unroll
    for (int mi = 0; mi < 4; ++mi)
      af[mi] = *(const bf16x8*)(&As[cur][(rA + mi * 16) * 32 + gA]);
#pragma unroll
    for (int nj = 0; nj < 4; ++nj)
      bfr[nj] = *(const bf16x8*)(&Bs[cur][(rB + nj * 16) * 32 + gB]);
    asm volatile("s_waitcnt lgkmcnt(0)" ::: "memory");
    __builtin_amdgcn_sched_barrier(0);
    __builtin_amdgcn_s_barrier();
    if (dostage) stage(cur, ktnext);
    __builtin_amdgcn_sched_barrier(0);
    __builtin_amdgcn_s_setprio(1);
#pragma unroll
    for (int mi = 0; mi < 4; ++mi)
#pragma unroll
      for (int nj = 0; nj < 4; ++nj)
        acc[mi][nj] = MFMA16(af[mi], bfr[nj], acc[mi][nj], 0, 0, 0);
    __builtin_amdgcn_s_setprio(0);
  };

  stage(0, 0);
  stage(1, 1);
#pragma unroll
  for (int kt = 0; kt < 10; ++kt) {
    VMWAIT(4);
    kbody(kt & 1, kt + 2, true);
  }
  VMWAIT(4);
  kbody(0, 0, false);
  VMWAIT(0);
  kbody(1, 0, false);

#pragma unroll
  for (int mi = 0; mi < 4; ++mi) {
    const int ch = cb + (w >> 1) * 64 + mi * 16 + (l >> 4) * 4;
    const f32x4 bv = *(const f32x4*)(bias + ch);
#pragma unroll
    for (int nj = 0; nj < 4; ++nj) {
      const int tok = tb + (w & 1) * 64 + nj * 16 + (l & 15);
      if constexpr (QKV) {
        const float scl = (ch < 384) ? QSCALE : 1.0f;
        u16x4 pk;
#pragma unroll
        for (int r = 0; r < 4; ++r) pk[r] = f2bf((acc[mi][nj][r] + bv[r]) * scl);
        *(u16x4*)((u16*)outp + (size_t)tok * LDC + ch) = pk;
      } else {
        f32x4 o;
#pragma unroll
        for (int r = 0; r < 4; ++r) o[r] = acc[mi][nj][r] + bv[r];
        *(f32x4*)((float*)outp + (size_t)tok * LDC + ch) = o;
      }
    }
  }
}

// ---------------- Attention (round-6 layout + smask2 f32x4 + head prefetch)
__global__ __launch_bounds__(256) void attn_kernel(
    const u16* __restrict__ qkvb, const float* __restrict__ smask2,
    u16* __restrict__ attnb) {
  __shared__ u16 Pl[4][64 * 72];   // P per wave: [n][k], stride 72 u16
  __shared__ u16 Vt[4][2336];      // V^T per wave: [d][k], addr d*72+(d>>3)*8+k
  const int t = threadIdx.x;
  const int l = t & 63, w = t >> 6;
  const int b = blockIdx.x;
  u16* Pw = &Pl[w][0];
  u16* Vw = &Vt[w][0];
  const u16x8 z = {0, 0, 0, 0, 0, 0, 0, 0};

  // prefetched per-head registers
  bf16x8 qa[4], kb[4];
  u16x8 vv[4];
  {
    const u16* base = qkvb + (size_t)b * 49 * 1152 + w * 32 + (l >> 4) * 8;
#pragma unroll
    for (int mi = 0; mi < 4; ++mi) {
      const int n = mi * 16 + (l & 15);
      qa[mi] = (n < 49) ? *(const bf16x8*)(base + (size_t)n * 1152) : as_bf(z);
      kb[mi] = (n < 49) ? *(const bf16x8*)(base + 384 + (size_t)n * 1152) : as_bf(z);
    }
#pragma unroll
    for (int i = 0; i < 4; ++i) {
      const int row = i * 16 + (l >> 2);
      vv[i] = (row < 49)
          ? *(const u16x8*)(qkvb + (size_t)(b * 49 + row) * 1152 + 768 + w * 32 + (l & 3) * 8)
          : z;
    }
  }

#pragma unroll
  for (int hi = 0; hi < 3; ++hi) {
    const int h = w + hi * 4;

    // V^T scatter (current head, from prefetched regs)
#pragma unroll
    for (int i = 0; i < 4; ++i) {
      const int row = i * 16 + (l >> 2);
      const int sgg = l & 3;
#pragma unroll
      for (int e = 0; e < 8; ++e) {
        const int d = sgg * 8 + e;
        Vw[d * 72 + (d >> 3) * 8 + row] = vv[i][e];
      }
    }

    // S = q k^T
    f32x4 s[4][4];
    __builtin_amdgcn_s_setprio(1);
#pragma unroll
    for (int mi = 0; mi < 4; ++mi)
#pragma unroll
      for (int nj = 0; nj < 4; ++nj) s[mi][nj] = MFMA16(qa[mi], kb[nj], zf4(), 0, 0, 0);
    __builtin_amdgcn_s_setprio(0);

    // prefetch next head's Q/K/V; latency hides under softmax VALU
    if (hi < 2) {
      const u16* base2 = qkvb + (size_t)b * 49 * 1152 + (h + 4) * 32 + (l >> 4) * 8;
#pragma unroll
      for (int mi = 0; mi < 4; ++mi) {
        const int n = mi * 16 + (l & 15);
        qa[mi] = (n < 49) ? *(const bf16x8*)(base2 + (size_t)n * 1152) : as_bf(z);
        kb[mi] = (n < 49) ? *(const bf16x8*)(base2 + 384 + (size_t)n * 1152) : as_bf(z);
      }
#pragma unroll
      for (int i = 0; i < 4; ++i) {
        const int row = i * 16 + (l >> 2);
        vv[i] = (row < 49)
            ? *(const u16x8*)(qkvb + (size_t)(b * 49 + row) * 1152 + 768 + (h + 4) * 32 + (l & 3) * 8)
            : z;
      }
    }

    // bias + shift mask via vectorized smask2 reads
    const float* sm2 = smask2 + ((size_t)(b & 3) * 12 + h) * 3136;
#pragma unroll
    for (int mi = 0; mi < 4; ++mi) {
#pragma unroll
      for (int r = 0; r < 4; ++r) {
        const int n = mi * 16 + (l >> 4) * 4 + r;
        if (n < 49) {
          const f32x4 bv = *(const f32x4*)(sm2 + n * 64 + (l & 15) * 4);
          s[mi][0][r] += bv[0];
          s[mi][1][r] += bv[1];
          s[mi][2][r] += bv[2];
          s[mi][3][r] = ((l & 15) == 0) ? s[mi][3][r] + bv[3] : -1e30f;
        }
      }
    }
    // softmax (DPP reduce over 16-lane groups)
#pragma unroll
    for (int mi = 0; mi < 4; ++mi) {
#pragma unroll
      for (int r = 0; r < 4; ++r) {
        float mx = fmaxf(fmaxf(s[mi][0][r], s[mi][1][r]), fmaxf(s[mi][2][r], s[mi][3][r]));
        mx = rmax16(mx);
        float e0 = 0.f;
#pragma unroll
        for (int nj = 0; nj < 4; ++nj) {
          const float p = __expf(s[mi][nj][r] - mx);
          s[mi][nj][r] = p;
          e0 += p;
        }
        e0 = rsum16(e0);
        const float inv = 1.0f / e0;
#pragma unroll
        for (int nj = 0; nj < 4; ++nj) s[mi][nj][r] *= inv;
      }
    }
    // P -> LDS bf16 ([n][k], stride 72)
#pragma unroll
    for (int mi = 0; mi < 4; ++mi)
#pragma unroll
      for (int r = 0; r < 4; ++r) {
        const int row = mi * 16 + (l >> 4) * 4 + r;
#pragma unroll
        for (int nj = 0; nj < 4; ++nj)
          Pw[row * 72 + nj * 16 + (l & 15)] = f2bf(s[mi][nj][r]);
      }
    asm volatile("s_waitcnt lgkmcnt(0)" ::: "memory");
    __builtin_amdgcn_sched_barrier(0);

    // O^T[d][n] = sum_k V^T[d][k] P^T[k][n]
    f32x4 ot[2][4];
#pragma unroll
    for (int dj = 0; dj < 2; ++dj)
#pragma unroll
      for (int mi = 0; mi < 4; ++mi) ot[dj][mi] = zf4();
#pragma unroll
    for (int ks = 0; ks < 2; ++ks) {
      bf16x8 va[2], pb[4];
#pragma unroll
      for (int dj = 0; dj < 2; ++dj) {
        const int d0 = dj * 16 + (l & 15);
        va[dj] = *(const bf16x8*)(Vw + d0 * 72 + (d0 >> 3) * 8 + ks * 32 + (l >> 4) * 8);
      }
#pragma unroll
      for (int mi = 0; mi < 4; ++mi)
        pb[mi] = *(const bf16x8*)(Pw + (mi * 16 + (l & 15)) * 72 + ks * 32 + (l >> 4) * 8);
      __builtin_amdgcn_s_setprio(1);
#pragma unroll
      for (int dj = 0; dj < 2; ++dj)
#pragma unroll
        for (int mi = 0; mi < 4; ++mi)
          ot[dj][mi] = MFMA16(va[dj], pb[mi], ot[dj][mi], 0, 0, 0);
      __builtin_amdgcn_s_setprio(0);
    }
    // store O^T
#pragma unroll
    for (int dj = 0; dj < 2; ++dj)
#pragma unroll
      for (int mi = 0; mi < 4; ++mi) {
        const int n = mi * 16 + (l & 15);
        if (n < 49) {
          u16x4 pk;
          pk[0] = f2bf(ot[dj][mi][0]);
          pk[1] = f2bf(ot[dj][mi][1]);
          pk[2] = f2bf(ot[dj][mi][2]);
          pk[3] = f2bf(ot[dj][mi][3]);
          *(u16x4*)(attnb + (size_t)(b * 49 + n) * 384 + h * 32 + dj * 16 + (l >> 4) * 4) = pk;
        }
      }
    asm volatile("s_waitcnt lgkmcnt(0)" ::: "memory");
    __builtin_amdgcn_sched_barrier(0);
  }
}

extern "C" void kernel_launch(void* const* d_in, const int* in_sizes, int n_in,
                              void* d_out, int out_size, void* d_ws, size_t ws_size,
                              hipStream_t stream) {
  const float* x       = (const float*)d_in[0];
  const float* mask    = (const float*)d_in[1];
  const float* w_qkv   = (const float*)d_in[2];
  const float* b_qkv   = (const float*)d_in[3];
  const float* bias_t  = (const float*)d_in[4];
  const float* w_proj  = (const float*)d_in[5];
  const float* b_proj  = (const float*)d_in[6];
  const int*   rel_idx = (const int*)d_in[7];
  float* out = (float*)d_out;

  char* ws = (char*)d_ws;
  u16*   wqT    = (u16*)ws;                      // 442368 u16
  u16*   wpT    = (u16*)(ws + 884736);           // 147456 u16
  float* smask2 = (float*)(ws + 1179648);        // 150528 f32 (602112 B)
  u16*   qkvb   = (u16*)(ws + 1781760);          // 200704*1152 u16
  u16*   xb     = (u16*)(ws + 464203776);        // 200704*384 u16 (aliases attnb)
  u16*   attnb  = (u16*)(ws + 464203776);        // xb dead before attn writes

  prep_kernel<<<2892, 256, 0, stream>>>(w_qkv, w_proj, bias_t, rel_idx, mask,
                                        wqT, wpT, smask2);
  conv_x<<<37632, 256, 0, stream>>>(x, xb);
  gemm4<9, true><<<14112, 256, 0, stream>>>(wqT, xb, b_qkv, qkvb);
  attn_kernel<<<4096, 256, 0, stream>>>(qkvb, smask2, attnb);
  gemm4<3, false><<<4704, 256, 0, stream>>>(wpT, attnb, b_proj, out);
}

// Round 9
// 809.104 us; speedup vs baseline: 1.4486x; 1.0768x over previous
//
#include <hip/hip_runtime.h>

typedef unsigned short u16;
typedef u16 u16x4 __attribute__((ext_vector_type(4)));
typedef u16 u16x8 __attribute__((ext_vector_type(8)));
typedef __bf16 bf16x8 __attribute__((ext_vector_type(8)));
typedef float f32x4 __attribute__((ext_vector_type(4)));

#define MFMA16 __builtin_amdgcn_mfma_f32_16x16x32_bf16
#define QSCALE 0.17677669529663689f
#define VMWAIT(N) asm volatile("s_waitcnt vmcnt(" #N ")" ::: "memory")

__device__ __forceinline__ u16 f2bf(float f) {
  unsigned u = __builtin_bit_cast(unsigned, f);
  u += 0x7fffu + ((u >> 16) & 1u);
  return (u16)(u >> 16);
}
__device__ __forceinline__ bf16x8 as_bf(u16x8 u) { return __builtin_bit_cast(bf16x8, u); }
__device__ __forceinline__ f32x4 zf4() { f32x4 z = {0.f, 0.f, 0.f, 0.f}; return z; }

template <int CTRL>
__device__ __forceinline__ float dppf(float x) {
  int i = __builtin_bit_cast(int, x);
  int r = __builtin_amdgcn_update_dpp(i, i, CTRL, 0xf, 0xf, false);
  return __builtin_bit_cast(float, r);
}
__device__ __forceinline__ float rmax16(float x) {
  x = fmaxf(x, dppf<0xB1>(x));
  x = fmaxf(x, dppf<0x4E>(x));
  x = fmaxf(x, dppf<0x124>(x));
  x = fmaxf(x, dppf<0x128>(x));
  return x;
}
__device__ __forceinline__ float rsum16(float x) {
  x += dppf<0xB1>(x);
  x += dppf<0x4E>(x);
  x += dppf<0x124>(x);
  x += dppf<0x128>(x);
  return x;
}

// ---------------- prep: weight transpose->bf16, smask2 build ---------------
// smask2 layout: [g][h][n][lane(16)][nj(4)], m = nj*16+lane.
__global__ __launch_bounds__(256) void prep_kernel(
    const float* __restrict__ wq, const float* __restrict__ wp,
    const float* __restrict__ bt, const int* __restrict__ ri,
    const float* __restrict__ mask,
    u16* __restrict__ wqT, u16* __restrict__ wpT, float* __restrict__ smask2) {
  int idx = blockIdx.x * 256 + threadIdx.x;
  if (idx < 442368) {
    int nn = idx / 384, kk = idx % 384;
    wqT[idx] = f2bf(wq[(size_t)kk * 1152 + nn]);
  } else if (idx < 589824) {
    int i2 = idx - 442368;
    int nn = i2 / 384, kk = i2 % 384;
    wpT[i2] = f2bf(wp[(size_t)kk * 384 + nn]);
  } else if (idx < 740352) {
    int i3 = idx - 589824;
    int g = i3 / 37632;
    int rem = i3 % 37632;
    int h = rem / 3136;
    int nm = rem % 3136;
    int n = nm >> 6;
    int r2 = nm & 63;
    int lane = r2 >> 2, nj = r2 & 3;
    int m = nj * 16 + lane;
    float v = 0.f;
    if (m < 49 && n < 49)
      v = bt[ri[n * 49 + m] * 12 + h] + mask[g * 2401 + n * 49 + m];
    smask2[i3] = v;
  }
}

// ---------------- conv_x: fp32 x -> bf16 (one pass) ------------------------
__global__ __launch_bounds__(256) void conv_x(const float* __restrict__ x,
                                              u16* __restrict__ xb) {
  size_t i = ((size_t)blockIdx.x * 256 + threadIdx.x) * 8;
  f32x4 a = *(const f32x4*)(x + i);
  f32x4 b = *(const f32x4*)(x + i + 4);
  u16x8 o;
  o[0] = f2bf(a[0]); o[1] = f2bf(a[1]); o[2] = f2bf(a[2]); o[3] = f2bf(a[3]);
  o[4] = f2bf(b[0]); o[5] = f2bf(b[1]); o[6] = f2bf(b[2]); o[7] = f2bf(b[3]);
  *(u16x8*)(xb + i) = o;
}

// ---------------- GEMM v4 (verified): C^T, BK=32, counted vmcnt ------------
template <int NCH, bool QKV>
__global__ __launch_bounds__(256) void gemm4(
    const u16* __restrict__ Wt, const u16* __restrict__ Xb,
    const float* __restrict__ bias, void* __restrict__ outp) {
  __shared__ u16 As[2][128 * 32];
  __shared__ u16 Bs[2][128 * 32];
  const int t = threadIdx.x;
  const int l = t & 63, w = t >> 6;

  const int bid = blockIdx.x;
  const int xcd = bid & 7, q = bid >> 3;
  const int logical = xcd * (196 * NCH) + q;
  const int tokt = logical / NCH, cht = logical % NCH;
  const int tb = tokt * 128;
  const int cb = cht * 128;
  const int LDC = NCH * 128;

  f32x4 acc[4][4];
#pragma unroll
  for (int mi = 0; mi < 4; ++mi)
#pragma unroll
    for (int ni = 0; ni < 4; ++ni) acc[mi][ni] = zf4();

  const int rA = (w >> 1) * 64 + (l & 15);
  const int rB = (w & 1) * 64 + (l & 15);
  const int gsel = l >> 4;
  const int gA = ((gsel ^ ((rA >> 1) & 3))) * 8;
  const int gB = ((gsel ^ ((rB >> 1) & 3))) * 8;

  auto stage = [&](int bf, int kt) {
    const int ko = kt * 32;
#pragma unroll
    for (int j = 0; j < 2; ++j) {
      const int gi = j * 256 + t;
      const int row = gi >> 2, slot = gi & 3;
      const int sg = (slot ^ ((row >> 1) & 3)) * 8;
      __builtin_amdgcn_global_load_lds(
          (const __attribute__((address_space(1))) unsigned int*)
              (Wt + (size_t)(cb + row) * 384 + ko + sg),
          (__attribute__((address_space(3))) unsigned int*)(&As[bf][gi * 8]),
          16, 0, 0);
      __builtin_amdgcn_global_load_lds(
          (const __attribute__((address_space(1))) unsigned int*)
              (Xb + (size_t)(tb + row) * 384 + ko + sg),
          (__attribute__((address_space(3))) unsigned int*)(&Bs[bf][gi * 8]),
          16, 0, 0);
    }
  };

  auto kbody = [&](int cur, int ktnext, bool dostage) {
    __builtin_amdgcn_sched_barrier(0);
    __builtin_amdgcn_s_barrier();
    bf16x8 af[4], bfr[4];
#pragma unroll
    for (int mi = 0; mi < 4; ++mi)
      af[mi] = *(const bf16x8*)(&As[cur][(rA + mi * 16) * 32 + gA]);
#pragma unroll
    for (int nj = 0; nj < 4; ++nj)
      bfr[nj] = *(const bf16x8*)(&Bs[cur][(rB + nj * 16) * 32 + gB]);
    asm volatile("s_waitcnt lgkmcnt(0)" ::: "memory");
    __builtin_amdgcn_sched_barrier(0);
    __builtin_amdgcn_s_barrier();
    if (dostage) stage(cur, ktnext);
    __builtin_amdgcn_sched_barrier(0);
    __builtin_amdgcn_s_setprio(1);
#pragma unroll
    for (int mi = 0; mi < 4; ++mi)
#pragma unroll
      for (int nj = 0; nj < 4; ++nj)
        acc[mi][nj] = MFMA16(af[mi], bfr[nj], acc[mi][nj], 0, 0, 0);
    __builtin_amdgcn_s_setprio(0);
  };

  stage(0, 0);
  stage(1, 1);
#pragma unroll
  for (int kt = 0; kt < 10; ++kt) {
    VMWAIT(4);
    kbody(kt & 1, kt + 2, true);
  }
  VMWAIT(4);
  kbody(0, 0, false);
  VMWAIT(0);
  kbody(1, 0, false);

#pragma unroll
  for (int mi = 0; mi < 4; ++mi) {
    const int ch = cb + (w >> 1) * 64 + mi * 16 + (l >> 4) * 4;
    const f32x4 bv = *(const f32x4*)(bias + ch);
#pragma unroll
    for (int nj = 0; nj < 4; ++nj) {
      const int tok = tb + (w & 1) * 64 + nj * 16 + (l & 15);
      if constexpr (QKV) {
        const float scl = (ch < 384) ? QSCALE : 1.0f;
        u16x4 pk;
#pragma unroll
        for (int r = 0; r < 4; ++r) pk[r] = f2bf((acc[mi][nj][r] + bv[r]) * scl);
        *(u16x4*)((u16*)outp + (size_t)tok * LDC + ch) = pk;
      } else {
        f32x4 o;
#pragma unroll
        for (int r = 0; r < 4; ++r) o[r] = acc[mi][nj][r] + bv[r];
        *(f32x4*)((float*)outp + (size_t)tok * LDC + ch) = o;
      }
    }
  }
}

// ---------------- Attention v9: 1 block = 1 window, 12 waves = 12 heads ----
// No serial head loop.  Per-wave LDS: compact P [64][64] granule-XOR swizzle
// (round-7 correctness-verified) + V^T stride-72.  154.4 KB -> 12 waves/CU.
// XCD-affine window mapping matches gemm4's token ownership.
__global__ __launch_bounds__(768, 3) void attn_kernel(
    const u16* __restrict__ qkvb, const float* __restrict__ smask2,
    u16* __restrict__ attnb) {
  __shared__ u16 Pl[12][4096];     // per-head P: [n][m] compact swizzled
  __shared__ u16 Vt[12][2336];     // per-head V^T: [d][k] stride 72 + skew
  const int t = threadIdx.x;
  const int l = t & 63, wv = t >> 6;       // wv = head 0..11
  const int bid = blockIdx.x;
  const int b = (bid & 7) * 512 + (bid >> 3);   // window, XCD-affine
  const int h = wv;
  u16* Pw = &Pl[wv][0];
  u16* Vw = &Vt[wv][0];
  const u16x8 z = {0, 0, 0, 0, 0, 0, 0, 0};

  // V^T staging: load V rows, scatter to [d][k]
#pragma unroll
  for (int i = 0; i < 4; ++i) {
    const int row = i * 16 + (l >> 2);
    const int sg = l & 3;
    u16x8 vv = z;
    if (row < 49)
      vv = *(const u16x8*)(qkvb + (size_t)(b * 49 + row) * 1152 + 768 + h * 32 + sg * 8);
#pragma unroll
    for (int e = 0; e < 8; ++e) {
      const int d = sg * 8 + e;
      Vw[d * 72 + (d >> 3) * 8 + row] = vv[e];
    }
  }

  // q (A-frag) / k (B-frag) from global
  const u16* base = qkvb + (size_t)b * 49 * 1152 + h * 32 + (l >> 4) * 8;
  bf16x8 qa[4], kb[4];
#pragma unroll
  for (int mi = 0; mi < 4; ++mi) {
    const int n = mi * 16 + (l & 15);
    qa[mi] = (n < 49) ? *(const bf16x8*)(base + (size_t)n * 1152) : as_bf(z);
    kb[mi] = (n < 49) ? *(const bf16x8*)(base + 384 + (size_t)n * 1152) : as_bf(z);
  }

  // S = q k^T
  f32x4 s[4][4];
  __builtin_amdgcn_s_setprio(1);
#pragma unroll
  for (int mi = 0; mi < 4; ++mi)
#pragma unroll
    for (int nj = 0; nj < 4; ++nj) s[mi][nj] = MFMA16(qa[mi], kb[nj], zf4(), 0, 0, 0);
  __builtin_amdgcn_s_setprio(0);

  // bias + shift mask (vectorized smask2)
  const float* sm2 = smask2 + ((size_t)(b & 3) * 12 + h) * 3136;
#pragma unroll
  for (int mi = 0; mi < 4; ++mi) {
#pragma unroll
    for (int r = 0; r < 4; ++r) {
      const int n = mi * 16 + (l >> 4) * 4 + r;
      if (n < 49) {
        const f32x4 bv = *(const f32x4*)(sm2 + n * 64 + (l & 15) * 4);
        s[mi][0][r] += bv[0];
        s[mi][1][r] += bv[1];
        s[mi][2][r] += bv[2];
        s[mi][3][r] = ((l & 15) == 0) ? s[mi][3][r] + bv[3] : -1e30f;
      }
    }
  }
  // softmax (DPP reduce over 16-lane groups)
#pragma unroll
  for (int mi = 0; mi < 4; ++mi) {
#pragma unroll
    for (int r = 0; r < 4; ++r) {
      float mx = fmaxf(fmaxf(s[mi][0][r], s[mi][1][r]), fmaxf(s[mi][2][r], s[mi][3][r]));
      mx = rmax16(mx);
      float e0 = 0.f;
#pragma unroll
      for (int nj = 0; nj < 4; ++nj) {
        const float p = __expf(s[mi][nj][r] - mx);
        s[mi][nj][r] = p;
        e0 += p;
      }
      e0 = rsum16(e0);
      const float inv = 1.0f / e0;
#pragma unroll
      for (int nj = 0; nj < 4; ++nj) s[mi][nj][r] *= inv;
    }
  }
  // P -> LDS bf16, compact swizzle: addr = row*64 + ((col>>3)^(row&7))*8 + (col&7)
#pragma unroll
  for (int mi = 0; mi < 4; ++mi)
#pragma unroll
    for (int r = 0; r < 4; ++r) {
      const int row = mi * 16 + (l >> 4) * 4 + r;
#pragma unroll
      for (int nj = 0; nj < 4; ++nj) {
        const int col = nj * 16 + (l & 15);
        Pw[row * 64 + (((col >> 3) ^ (row & 7)) * 8) + (col & 7)] = f2bf(s[mi][nj][r]);
      }
    }
  // drain this wave's LDS writes (V^T + P); waves own disjoint regions
  asm volatile("s_waitcnt lgkmcnt(0)" ::: "memory");
  __builtin_amdgcn_sched_barrier(0);

  // O^T[d][n] = sum_k V^T[d][k] P^T[k][n]
  f32x4 ot[2][4];
#pragma unroll
  for (int dj = 0; dj < 2; ++dj)
#pragma unroll
    for (int mi = 0; mi < 4; ++mi) ot[dj][mi] = zf4();
#pragma unroll
  for (int ks = 0; ks < 2; ++ks) {
    bf16x8 va[2], pb[4];
#pragma unroll
    for (int dj = 0; dj < 2; ++dj) {
      const int d0 = dj * 16 + (l & 15);
      va[dj] = *(const bf16x8*)(Vw + d0 * 72 + (d0 >> 3) * 8 + ks * 32 + (l >> 4) * 8);
    }
#pragma unroll
    for (int mi = 0; mi < 4; ++mi) {
      const int row = mi * 16 + (l & 15);
      pb[mi] = *(const bf16x8*)(Pw + row * 64 + (((ks * 4 + (l >> 4)) ^ (l & 7)) * 8));
    }
    __builtin_amdgcn_s_setprio(1);
#pragma unroll
    for (int dj = 0; dj < 2; ++dj)
#pragma unroll
      for (int mi = 0; mi < 4; ++mi)
        ot[dj][mi] = MFMA16(va[dj], pb[mi], ot[dj][mi], 0, 0, 0);
    __builtin_amdgcn_s_setprio(0);
  }
  // store O^T
#pragma unroll
  for (int dj = 0; dj < 2; ++dj)
#pragma unroll
    for (int mi = 0; mi < 4; ++mi) {
      const int n = mi * 16 + (l & 15);
      if (n < 49) {
        u16x4 pk;
        pk[0] = f2bf(ot[dj][mi][0]);
        pk[1] = f2bf(ot[dj][mi][1]);
        pk[2] = f2bf(ot[dj][mi][2]);
        pk[3] = f2bf(ot[dj][mi][3]);
        *(u16x4*)(attnb + (size_t)(b * 49 + n) * 384 + h * 32 + dj * 16 + (l >> 4) * 4) = pk;
      }
    }
}

extern "C" void kernel_launch(void* const* d_in, const int* in_sizes, int n_in,
                              void* d_out, int out_size, void* d_ws, size_t ws_size,
                              hipStream_t stream) {
  const float* x       = (const float*)d_in[0];
  const float* mask    = (const float*)d_in[1];
  const float* w_qkv   = (const float*)d_in[2];
  const float* b_qkv   = (const float*)d_in[3];
  const float* bias_t  = (const float*)d_in[4];
  const float* w_proj  = (const float*)d_in[5];
  const float* b_proj  = (const float*)d_in[6];
  const int*   rel_idx = (const int*)d_in[7];
  float* out = (float*)d_out;

  char* ws = (char*)d_ws;
  u16*   wqT    = (u16*)ws;                      // 442368 u16
  u16*   wpT    = (u16*)(ws + 884736);           // 147456 u16
  float* smask2 = (float*)(ws + 1179648);        // 150528 f32 (602112 B)
  u16*   qkvb   = (u16*)(ws + 1781760);          // 200704*1152 u16
  u16*   xb     = (u16*)(ws + 464203776);        // 200704*384 u16 (aliases attnb)
  u16*   attnb  = (u16*)(ws + 464203776);        // xb dead before attn writes

  prep_kernel<<<2892, 256, 0, stream>>>(w_qkv, w_proj, bias_t, rel_idx, mask,
                                        wqT, wpT, smask2);
  conv_x<<<37632, 256, 0, stream>>>(x, xb);
  gemm4<9, true><<<14112, 256, 0, stream>>>(wqT, xb, b_qkv, qkvb);
  attn_kernel<<<4096, 768, 0, stream>>>(qkvb, smask2, attnb);
  gemm4<3, false><<<4704, 256, 0, stream>>>(wpT, attnb, b_proj, out);
}